// Round 1
// baseline (3603.339 us; speedup 1.0000x reference)
//
#include <hip/hip_runtime.h>

// PlasticLSTM: T=256, B=32, I=128, H=256, 4H=1024, CLIP=2
// d_in: x[T,B,I], Wx[4H,I], bx[4H], Wh[4H,H], bh[4H], w_mod[1,H], b_mod[1],
//       w_fan[H,1], b_fan[H], alpha[H,H]   (all fp32)
// d_out: hs[T,B,H] ++ h[B,H] ++ c[B,H] ++ hebb[B,H,H]  (fp32, concat flat)

#define TT 256
#define BB 32
#define II 128
#define HH 256
#define G4 1024

__device__ __forceinline__ float sigm(float x) {
    return 1.0f / (1.0f + __expf(-x));
}
__device__ __forceinline__ float tanhfast(float x) {
    // tanh(x) = 1 - 2/(e^{2x}+1); saturates correctly at +-inf
    return 1.0f - 2.0f / (__expf(2.0f * x) + 1.0f);
}

// ---------------------------------------------------------------------------
// Prep: Wq4[r4*1024 + g] = float4{ Wh[g][4*r4 .. 4*r4+3] }
// i.e. transposed (r-major) Wh with 4 consecutive r interleaved per float4,
// so the scan's gate loop does one coalesced 16B load per 4 K-steps.
// ---------------------------------------------------------------------------
__global__ __launch_bounds__(256) void prep_wq(const float* __restrict__ Wh,
                                               float4* __restrict__ Wq4) {
    int idx = blockIdx.x * 256 + threadIdx.x;   // 65536 float4s
    int r4 = idx >> 10;
    int g  = idx & 1023;
    Wq4[idx] = *(const float4*)(Wh + g * HH + (r4 << 2));
}

// ---------------------------------------------------------------------------
// xf[t,b,g] = sum_i x[t,b,i]*Wx[g,i] + bx[g] + bh[g]
// M = T*B = 8192, N = 4H = 1024, K = I = 128.  64x64 tile, K-chunks of 32.
// ---------------------------------------------------------------------------
__global__ __launch_bounds__(256) void xf_gemm(const float* __restrict__ x,
                                               const float* __restrict__ Wx,
                                               const float* __restrict__ bx,
                                               const float* __restrict__ bh,
                                               float* __restrict__ xf) {
    __shared__ float As[64][37];   // pad 37: 2-way max bank aliasing (free)
    __shared__ float Bs[64][37];
    const int tid = threadIdx.x;
    const int tx = tid & 15, ty = tid >> 4;
    const int m0 = blockIdx.y << 6;
    const int n0 = blockIdx.x << 6;
    float c[4][4] = {};

    for (int k0 = 0; k0 < II; k0 += 32) {
#pragma unroll
        for (int hh = 0; hh < 2; ++hh) {
            int row = (tid >> 3) + (hh << 5);
            int col = (tid & 7) << 2;
            float4 va = *(const float4*)(x + (size_t)(m0 + row) * II + k0 + col);
            As[row][col] = va.x; As[row][col + 1] = va.y;
            As[row][col + 2] = va.z; As[row][col + 3] = va.w;
            float4 vb = *(const float4*)(Wx + (size_t)(n0 + row) * II + k0 + col);
            Bs[row][col] = vb.x; Bs[row][col + 1] = vb.y;
            Bs[row][col + 2] = vb.z; Bs[row][col + 3] = vb.w;
        }
        __syncthreads();
#pragma unroll
        for (int kk = 0; kk < 32; ++kk) {
            float a[4], bb[4];
#pragma unroll
            for (int u = 0; u < 4; ++u) a[u] = As[(ty << 2) + u][kk];
#pragma unroll
            for (int v = 0; v < 4; ++v) bb[v] = Bs[(tx << 2) + v][kk];
#pragma unroll
            for (int u = 0; u < 4; ++u)
#pragma unroll
                for (int v = 0; v < 4; ++v)
                    c[u][v] = fmaf(a[u], bb[v], c[u][v]);
        }
        __syncthreads();
    }
    const int n = n0 + (tx << 2);
    float4 bxv = *(const float4*)(bx + n);
    float4 bhv = *(const float4*)(bh + n);
    float4 badd = {bxv.x + bhv.x, bxv.y + bhv.y, bxv.z + bhv.z, bxv.w + bhv.w};
#pragma unroll
    for (int u = 0; u < 4; ++u) {
        int m = m0 + (ty << 2) + u;
        float4 o = {c[u][0] + badd.x, c[u][1] + badd.y,
                    c[u][2] + badd.z, c[u][3] + badd.w};
        *(float4*)(xf + (size_t)m * G4 + n) = o;
    }
}

// ---------------------------------------------------------------------------
// Recurrent scan: one block per batch element. 1024 threads.
// Thread t: gate output g = t; hebb column k = t&255, row group rg = t>>8
// (rows rg*64 .. rg*64+63) -> hebb[64] in VGPRs for the whole scan.
// 2 __syncthreads per step; zero inter-block communication.
// ---------------------------------------------------------------------------
__global__ __launch_bounds__(1024, 1) void scan_kernel(
    const float* __restrict__ xf,      // [T,B,4H] with bx+bh folded in
    const float4* __restrict__ Wq4,    // interleaved Wh^T
    const float* __restrict__ alpha,   // [H,H]
    const float* __restrict__ w_mod,   // [H]
    const float* __restrict__ b_mod,   // [1]
    const float* __restrict__ w_fan,   // [H]
    const float* __restrict__ b_fan,   // [H]
    float* __restrict__ out) {
    const int b   = blockIdx.x;
    const int tid = threadIdx.x;
    const int k   = tid & (HH - 1);
    const int rg  = tid >> 8;      // 0..3
    const int r0  = rg << 6;       // row base

    __shared__ float h_s[2][HH];
    __shared__ float c_s[HH];
    __shared__ float fioj_s[G4];
    __shared__ float pp_s[4][HH];
    __shared__ float j_s[HH];
    __shared__ float red_s[4];

    float hebb[64];
#pragma unroll
    for (int u = 0; u < 64; ++u) hebb[u] = 0.0f;

    if (tid < HH) {
        h_s[0][tid] = 0.0f;
        h_s[1][tid] = 0.0f;
        c_s[tid]    = 0.0f;
    }
    __syncthreads();

    const float bmod = b_mod[0];
    const float wf   = w_fan[k];
    const float bf   = b_fan[k];
    const float wm   = (tid < HH) ? w_mod[tid] : 0.0f;
    const float* ap  = alpha + (size_t)r0 * HH + k;

    for (int t = 0; t < TT; ++t) {
        const int p = t & 1;
        const float* hp = h_s[p];
        const float4* hp4 = (const float4*)hp;

        // --- Phase A: gate preactivation fioj[g], g = tid -----------------
        float4 acc4 = {0.f, 0.f, 0.f, 0.f};
#pragma unroll 4
        for (int r4 = 0; r4 < 64; ++r4) {
            float4 w  = Wq4[(r4 << 10) + tid];
            float4 hv = hp4[r4];
            acc4.x = fmaf(w.x, hv.x, acc4.x);
            acc4.y = fmaf(w.y, hv.y, acc4.y);
            acc4.z = fmaf(w.z, hv.z, acc4.z);
            acc4.w = fmaf(w.w, hv.w, acc4.w);
        }
        fioj_s[tid] = (acc4.x + acc4.y) + (acc4.z + acc4.w)
                    + xf[((size_t)t * BB + b) * G4 + tid];

        // --- Phase A2: plast partial for column k over rows r0..r0+63 -----
        float pp = 0.0f;
#pragma unroll
        for (int u4 = 0; u4 < 16; ++u4) {
            float4 hv = hp4[(r0 >> 2) + u4];
            pp = fmaf(hv.x * ap[(4 * u4 + 0) * HH], hebb[4 * u4 + 0], pp);
            pp = fmaf(hv.y * ap[(4 * u4 + 1) * HH], hebb[4 * u4 + 1], pp);
            pp = fmaf(hv.z * ap[(4 * u4 + 2) * HH], hebb[4 * u4 + 2], pp);
            pp = fmaf(hv.w * ap[(4 * u4 + 3) * HH], hebb[4 * u4 + 3], pp);
        }
        pp_s[rg][k] = pp;
        __syncthreads();

        // --- Phase B: elementwise cell update (threads 0..255) ------------
        if (tid < HH) {
            float fg = sigm(fioj_s[tid]);
            float ig = sigm(fioj_s[HH + tid]);
            float og = sigm(fioj_s[2 * HH + tid]);
            float jp = fioj_s[3 * HH + tid] + pp_s[0][tid] + pp_s[1][tid]
                     + pp_s[2][tid] + pp_s[3][tid];
            float jv = tanhfast(jp);
            float cn = fmaf(fg, c_s[tid], ig * jv);
            float hn = og * tanhfast(cn);
            c_s[tid]        = cn;
            j_s[tid]        = jv;
            h_s[p ^ 1][tid] = hn;
            out[((size_t)t * BB + b) * HH + tid] = hn;   // hs[t,b,:]
            // eta partial: sum_k cn*w_mod[k] ; waves 0..3 fully active
            float e = cn * wm;
#pragma unroll
            for (int m = 32; m >= 1; m >>= 1) e += __shfl_xor(e, m);
            if ((tid & 63) == 0) red_s[tid >> 6] = e;
        }
        __syncthreads();

        // --- Phase C: hebb update (all threads), reads h_old = hp ---------
        float eta = tanhfast(red_s[0] + red_s[1] + red_s[2] + red_s[3] + bmod);
        float mj  = fmaf(eta, wf, bf) * j_s[k];   // myeta[k] * j[k]
#pragma unroll
        for (int u4 = 0; u4 < 16; ++u4) {
            float4 hv = hp4[(r0 >> 2) + u4];
            hebb[4 * u4 + 0] = __builtin_amdgcn_fmed3f(
                fmaf(mj, hv.x, hebb[4 * u4 + 0]), -2.0f, 2.0f);
            hebb[4 * u4 + 1] = __builtin_amdgcn_fmed3f(
                fmaf(mj, hv.y, hebb[4 * u4 + 1]), -2.0f, 2.0f);
            hebb[4 * u4 + 2] = __builtin_amdgcn_fmed3f(
                fmaf(mj, hv.z, hebb[4 * u4 + 2]), -2.0f, 2.0f);
            hebb[4 * u4 + 3] = __builtin_amdgcn_fmed3f(
                fmaf(mj, hv.w, hebb[4 * u4 + 3]), -2.0f, 2.0f);
        }
        // barrier at top of next iteration separates C(t) reads of h_s[p]
        // from B(t+1) writes to h_s[p].
    }

    // --- Final state outputs ---------------------------------------------
    const size_t HS = (size_t)TT * BB * HH;
    if (tid < HH) {
        out[HS + (size_t)b * HH + tid]            = h_s[0][tid]; // TT even
        out[HS + BB * HH + (size_t)b * HH + tid]  = c_s[tid];
    }
    float* hebb_out = out + HS + 2 * BB * HH + (size_t)b * HH * HH;
#pragma unroll
    for (int u = 0; u < 64; ++u) {
        hebb_out[(size_t)(r0 + u) * HH + k] = hebb[u];
    }
}

// ---------------------------------------------------------------------------
extern "C" void kernel_launch(void* const* d_in, const int* in_sizes, int n_in,
                              void* d_out, int out_size, void* d_ws,
                              size_t ws_size, hipStream_t stream) {
    const float* x     = (const float*)d_in[0];
    const float* Wx    = (const float*)d_in[1];
    const float* bx    = (const float*)d_in[2];
    const float* Wh    = (const float*)d_in[3];
    const float* bh    = (const float*)d_in[4];
    const float* w_mod = (const float*)d_in[5];
    const float* b_mod = (const float*)d_in[6];
    const float* w_fan = (const float*)d_in[7];
    const float* b_fan = (const float*)d_in[8];
    const float* alpha = (const float*)d_in[9];
    float* out = (float*)d_out;

    float*  xf  = (float*)d_ws;                                   // 32 MiB
    float4* Wq4 = (float4*)((char*)d_ws + (size_t)TT * BB * G4 * 4); // 1 MiB

    hipLaunchKernelGGL(prep_wq, dim3(256), dim3(256), 0, stream, Wh, Wq4);
    hipLaunchKernelGGL(xf_gemm, dim3(16, 128), dim3(256), 0, stream,
                       x, Wx, bx, bh, xf);
    hipLaunchKernelGGL(scan_kernel, dim3(BB), dim3(1024), 0, stream,
                       xf, Wq4, alpha, w_mod, b_mod, w_fan, b_fan, out);
}